// Round 4
// baseline (1275.718 us; speedup 1.0000x reference)
//
#include <hip/hip_runtime.h>
#include <hip/hip_bf16.h>

// clusterLayer: q = rownorm( 1 / (1 + ||x||^2 + ||c||^2 - 2 x.cT) )
// N=524288, K=256, D=256. fp32 in/out.
// Kernel 0: clusters fp32 -> bf16 in 32x32x16-MFMA-fragment order
//   (1 KiB per (nj,ks) fragment, lane-contiguous) + fp32 c2 norms in ws.
// Main: no big LDS. Per block: 64 rows, 4 waves = 2 row-stripes x 2
//   col-halves. Per wave 32 rows x 128 cols -> acc = 64 regs; total
//   <=128 regs/lane (launch_bounds 256,4) -> 4 waves/SIMD.
//   B-frags global-loaded (L2-resident, coalesced), A streamed
//   global->reg->bf16, row sums combined across col-halves via tiny LDS.

#define DD 256
#define KC 256
#define BM 64
#define CL_SHORTS (KC * DD)            // 65536 shorts = 131072 B

typedef __attribute__((ext_vector_type(4)))  float f32x4;
typedef __attribute__((ext_vector_type(16))) float f32x16;
typedef __attribute__((ext_vector_type(8)))  short bf16x8;
typedef __attribute__((ext_vector_type(4)))  short bf16x4;

__device__ __forceinline__ short f2bf(float f) {
    union { float f; unsigned u; } v; v.f = f;
    unsigned r = (v.u + 0x7fffu + ((v.u >> 16) & 1u)) >> 16;
    return (short)r;
}

__device__ __forceinline__ f32x4 ld4(const float* p) { return *(const f32x4*)p; }

// ---------------- Kernel 0: prep clusters (fragment-order bf16 + norms) ----
__global__ __launch_bounds__(64)
void prep_clusters(const float* __restrict__ clus,
                   short* __restrict__ wsb, float* __restrict__ c2) {
    const int c = blockIdx.x;      // cluster row 0..255
    const int t = threadIdx.x;     // 0..63, 4 floats each
    f32x4 v = *(const f32x4*)(clus + c * DD + t * 4);
    bf16x4 o;
    o[0] = f2bf(v[0]); o[1] = f2bf(v[1]); o[2] = f2bf(v[2]); o[3] = f2bf(v[3]);

    // fragment layout: frag(nj,ks) = 512 contiguous shorts; within it,
    // lane (hi*32+l31) holds clusters[nj*32+l31][ks*16+hi*8 .. +8].
    const int j    = t >> 1;       // 8-elem chunk index within row (k/8)
    const int ks   = j >> 1;
    const int hi   = j & 1;
    const int half = t & 1;        // which 4-elem half of the chunk
    const int nj   = c >> 5;
    const int l31  = c & 31;
    *(bf16x4*)&wsb[(((nj * 16 + ks) * 64 + hi * 32 + l31) << 3) + half * 4] = o;

    float s = v[0]*v[0] + v[1]*v[1] + v[2]*v[2] + v[3]*v[3];
    s += __shfl_xor(s, 1);  s += __shfl_xor(s, 2);  s += __shfl_xor(s, 4);
    s += __shfl_xor(s, 8);  s += __shfl_xor(s, 16); s += __shfl_xor(s, 32);
    if (t == 0) c2[c] = s;
}

// ---------------- Main kernel ----------------
__global__ __launch_bounds__(256, 4)
void cluster_q_main(const float* __restrict__ ctx,
                    const short* __restrict__ wsb,
                    const float* __restrict__ c2g,
                    float* __restrict__ out) {
    __shared__ float rowsum[BM][2];

    const int t    = threadIdx.x;
    const int lane = t & 63;
    const int w    = t >> 6;                 // wave 0..3
    const int wsp  = w >> 1;                 // row-stripe 0..1 (32 rows each)
    const int wn   = w & 1;                  // col-half 0..1 (128 cols each)
    const int l31  = lane & 31;
    const int hi   = lane >> 5;
    const size_t row0 = (size_t)blockIdx.x * BM;

    const float* arow = ctx + (row0 + (size_t)(wsp * 32 + l31)) * DD + hi * 8;
    // B fragment base for this wave's first col-tile (nj_global = wn*4)
    const short* bl = wsb + (size_t)(wn * 4 * 16) * 512 + lane * 8;

    f32x16 acc[4];
#pragma unroll
    for (int j = 0; j < 4; ++j) acc[j] = (f32x16)0.f;

    // A ping-pong prefetch (2 steps ahead, 32 B/lane/step)
    f32x4 paA = ld4(arow),      pbA = ld4(arow + 4);
    f32x4 paB = ld4(arow + 16), pbB = ld4(arow + 20);

    // B ping-pong prefetch (1 step ahead)
    bf16x8 bA[4], bB[4];
#pragma unroll
    for (int j = 0; j < 4; ++j)
        bA[j] = *(const bf16x8*)(bl + (j * 16 + 0) * 512);

    float x2p = 0.f;

#pragma unroll
    for (int ks = 0; ks < 16; ++ks) {
        const bool even = (ks & 1) == 0;     // compile-time after unroll

        // issue next-step B loads into the other bank
        if (ks < 15) {
#pragma unroll
            for (int j = 0; j < 4; ++j) {
                bf16x8 v = *(const bf16x8*)(bl + (j * 16 + ks + 1) * 512);
                if (even) bB[j] = v; else bA[j] = v;
            }
        }

        // current A chunk, convert + |x|^2
        f32x4 a0 = even ? paA : paB;
        f32x4 a1 = even ? pbA : pbB;
        bf16x8 af;
        af[0] = f2bf(a0[0]); af[1] = f2bf(a0[1]);
        af[2] = f2bf(a0[2]); af[3] = f2bf(a0[3]);
        af[4] = f2bf(a1[0]); af[5] = f2bf(a1[1]);
        af[6] = f2bf(a1[2]); af[7] = f2bf(a1[3]);
        x2p += a0[0]*a0[0] + a0[1]*a0[1] + a0[2]*a0[2] + a0[3]*a0[3]
             + a1[0]*a1[0] + a1[1]*a1[1] + a1[2]*a1[2] + a1[3]*a1[3];

        // refill the just-consumed A bank with step ks+2
        if (ks < 14) {
            const float* ap = arow + (ks + 2) * 16;
            if (even) { paA = ld4(ap); pbA = ld4(ap + 4); }
            else      { paB = ld4(ap); pbB = ld4(ap + 4); }
        }

        // MFMA on current B bank
#pragma unroll
        for (int j = 0; j < 4; ++j) {
            bf16x8 bfr = even ? bA[j] : bB[j];
            acc[j] = __builtin_amdgcn_mfma_f32_32x32x16_bf16(af, bfr, acc[j], 0, 0, 0);
        }
    }

    // full-row |x|^2 (combine the two k-halves: lanes l and l^32)
    x2p += __shfl_xor(x2p, 32);

    float c2v[4];
#pragma unroll
    for (int j = 0; j < 4; ++j) c2v[j] = c2g[wn * 128 + j * 32 + l31];

    // ---- pass 1: q = 1/(1+d), per-row partial sums -> LDS ----
#pragma unroll
    for (int r = 0; r < 16; ++r) {
        const int rr = (r & 3) + 8 * (r >> 2) + 4 * hi;   // row within stripe
        const float x2r = __shfl(x2p, rr);                // lane rr has row rr
        float s = 0.f;
#pragma unroll
        for (int j = 0; j < 4; ++j) {
            float d = x2r + c2v[j] - 2.f * acc[j][r];
            float q = 1.f / (1.f + d);
            acc[j][r] = q;
            s += q;
        }
        s += __shfl_xor(s, 1);
        s += __shfl_xor(s, 2);
        s += __shfl_xor(s, 4);
        s += __shfl_xor(s, 8);
        s += __shfl_xor(s, 16);
        if (l31 == 0) rowsum[wsp * 32 + rr][wn] = s;
    }
    __syncthreads();

    // ---- pass 2: normalize + full-line stores ----
#pragma unroll
    for (int r = 0; r < 16; ++r) {
        const int rr = (r & 3) + 8 * (r >> 2) + 4 * hi;
        const int brow = wsp * 32 + rr;
        const float inv = 1.f / (rowsum[brow][0] + rowsum[brow][1]);
        float* op = out + (row0 + (size_t)brow) * KC + wn * 128 + l31;
#pragma unroll
        for (int j = 0; j < 4; ++j)
            op[j * 32] = acc[j][r] * inv;   // 2 x 128-B full lines / instr
    }
}

extern "C" void kernel_launch(void* const* d_in, const int* in_sizes, int n_in,
                              void* d_out, int out_size, void* d_ws, size_t ws_size,
                              hipStream_t stream) {
    const float* ctx  = (const float*)d_in[0];
    const float* clus = (const float*)d_in[1];
    float* out = (float*)d_out;

    short* wsb = (short*)d_ws;                               // bf16 fragment image
    float* c2  = (float*)((char*)d_ws + CL_SHORTS * 2);      // 256 fp32 norms

    const int nrows = in_sizes[0] / DD;                      // 524288
    const int grid  = nrows / BM;                            // 8192

    hipLaunchKernelGGL(prep_clusters, dim3(KC), dim3(64), 0, stream, clus, wsb, c2);
    hipLaunchKernelGGL(cluster_q_main, dim3(grid), dim3(256), 0, stream,
                       ctx, wsb, c2, out);
}

// Round 5
// 422.940 us; speedup vs baseline: 3.0163x; 3.0163x over previous
//
#include <hip/hip_runtime.h>
#include <hip/hip_bf16.h>

// clusterLayer: q = rownorm( 1 / (1 + ||x||^2 + ||c||^2 - 2 x.cT) )
// N=524288, K=256, D=256. fp32 in/out.
// Kernel 0: clusters fp32 -> bf16 in 32x32x16-MFMA-fragment order
//   (1 KiB per (nj,ks) fragment, lane-contiguous) + fp32 c2 norms in ws.
// Main: no big LDS, no K-loop barriers. Block = 256 thr = 4 waves =
//   4 col-quarters of one 32-row stripe. Per wave: 32 rows x 64 cols,
//   acc[2] = 32 regs; total ~100 unified regs -> ~5 waves/SIMD, no spill.
//   B-frags global-loaded (L2-resident, coalesced, ping-pong), A streamed
//   global->reg->bf16 (depth-3 rotating prefetch), row sums combined
//   across quarters via 512-B LDS + one barrier. Full-line stores.

#define DD 256
#define KC 256
#define BM 32
#define CL_SHORTS (KC * DD)            // 65536 shorts = 131072 B

typedef __attribute__((ext_vector_type(4)))  float f32x4;
typedef __attribute__((ext_vector_type(16))) float f32x16;
typedef __attribute__((ext_vector_type(8)))  short bf16x8;
typedef __attribute__((ext_vector_type(4)))  short bf16x4;

__device__ __forceinline__ short f2bf(float f) {
    union { float f; unsigned u; } v; v.f = f;
    unsigned r = (v.u + 0x7fffu + ((v.u >> 16) & 1u)) >> 16;
    return (short)r;
}

__device__ __forceinline__ f32x4 ld4(const float* p) { return *(const f32x4*)p; }

// ---------------- Kernel 0: prep clusters (fragment-order bf16 + norms) ----
__global__ __launch_bounds__(64)
void prep_clusters(const float* __restrict__ clus,
                   short* __restrict__ wsb, float* __restrict__ c2) {
    const int c = blockIdx.x;      // cluster row 0..255
    const int t = threadIdx.x;     // 0..63, 4 floats each
    f32x4 v = *(const f32x4*)(clus + c * DD + t * 4);
    bf16x4 o;
    o[0] = f2bf(v[0]); o[1] = f2bf(v[1]); o[2] = f2bf(v[2]); o[3] = f2bf(v[3]);

    // fragment layout: frag(nj,ks) = 512 contiguous shorts; within it,
    // lane (hi*32+l31) holds clusters[nj*32+l31][ks*16+hi*8 .. +8].
    const int j    = t >> 1;       // 8-elem chunk index within row (k/8)
    const int ks   = j >> 1;
    const int hi   = j & 1;
    const int half = t & 1;        // which 4-elem half of the chunk
    const int nj   = c >> 5;
    const int l31  = c & 31;
    *(bf16x4*)&wsb[(((nj * 16 + ks) * 64 + hi * 32 + l31) << 3) + half * 4] = o;

    float s = v[0]*v[0] + v[1]*v[1] + v[2]*v[2] + v[3]*v[3];
    s += __shfl_xor(s, 1);  s += __shfl_xor(s, 2);  s += __shfl_xor(s, 4);
    s += __shfl_xor(s, 8);  s += __shfl_xor(s, 16); s += __shfl_xor(s, 32);
    if (t == 0) c2[c] = s;
}

// ---------------- Main kernel ----------------
__global__ __launch_bounds__(256, 4)
void cluster_q_main(const float* __restrict__ ctx,
                    const short* __restrict__ wsb,
                    const float* __restrict__ c2g,
                    float* __restrict__ out) {
    __shared__ float rowsum[BM][4];

    const int t    = threadIdx.x;
    const int lane = t & 63;
    const int w    = t >> 6;                 // col-quarter 0..3 (64 cols each)
    const int l31  = lane & 31;
    const int hi   = lane >> 5;
    const size_t row0 = (size_t)blockIdx.x * BM;

    // A: lane l31 owns context row (row0+l31), hi selects the k-half
    const float* arow = ctx + (row0 + (size_t)l31) * DD + hi * 8;
    // B fragment base: global col-tile nj_g = w*2 + j, frag (nj_g*16+ks)*512
    const short* bl = wsb + (size_t)(w * 2 * 16) * 512 + lane * 8;

    f32x16 acc[2];
    acc[0] = (f32x16)0.f;
    acc[1] = (f32x16)0.f;

    // A rotating prefetch, depth 3 (32 B / lane / step)
    f32x4 pa[3], pb[3];
#pragma unroll
    for (int p = 0; p < 3; ++p) {
        pa[p] = ld4(arow + p * 16);
        pb[p] = ld4(arow + p * 16 + 4);
    }

    // B ping-pong prefetch, 1 step ahead
    bf16x8 bA[2], bB[2];
#pragma unroll
    for (int j = 0; j < 2; ++j)
        bA[j] = *(const bf16x8*)(bl + (j * 16 + 0) * 512);

    float x2p = 0.f;

#pragma unroll
    for (int ks = 0; ks < 16; ++ks) {
        const bool even = (ks & 1) == 0;     // compile-time after unroll
        const int slot  = ks % 3;            // compile-time after unroll

        // issue next-step B loads into the other bank
        if (ks < 15) {
#pragma unroll
            for (int j = 0; j < 2; ++j) {
                bf16x8 v = *(const bf16x8*)(bl + (j * 16 + ks + 1) * 512);
                if (even) bB[j] = v; else bA[j] = v;
            }
        }

        // current A chunk: convert + |x|^2
        f32x4 a0 = pa[slot], a1 = pb[slot];
        bf16x8 af;
        af[0] = f2bf(a0[0]); af[1] = f2bf(a0[1]);
        af[2] = f2bf(a0[2]); af[3] = f2bf(a0[3]);
        af[4] = f2bf(a1[0]); af[5] = f2bf(a1[1]);
        af[6] = f2bf(a1[2]); af[7] = f2bf(a1[3]);
        x2p += a0[0]*a0[0] + a0[1]*a0[1] + a0[2]*a0[2] + a0[3]*a0[3]
             + a1[0]*a1[0] + a1[1]*a1[1] + a1[2]*a1[2] + a1[3]*a1[3];

        // refill the just-consumed A slot with step ks+3
        if (ks < 13) {
            pa[slot] = ld4(arow + (ks + 3) * 16);
            pb[slot] = ld4(arow + (ks + 3) * 16 + 4);
        }

        // MFMA on current B bank
#pragma unroll
        for (int j = 0; j < 2; ++j) {
            bf16x8 bfr = even ? bA[j] : bB[j];
            acc[j] = __builtin_amdgcn_mfma_f32_32x32x16_bf16(af, bfr, acc[j], 0, 0, 0);
        }
    }

    // full-row |x|^2 (combine the two k-halves: lanes l and l^32)
    x2p += __shfl_xor(x2p, 32);

    float c2v[2];
#pragma unroll
    for (int j = 0; j < 2; ++j) c2v[j] = c2g[w * 64 + j * 32 + l31];

    // ---- pass 1: q = 1/(1+d), per-row partial sums -> LDS ----
#pragma unroll
    for (int r = 0; r < 16; ++r) {
        const int rr = (r & 3) + 8 * (r >> 2) + 4 * hi;   // row 0..31
        const float x2r = __shfl(x2p, rr);                // lane rr has row rr
        float s = 0.f;
#pragma unroll
        for (int j = 0; j < 2; ++j) {
            float d = x2r + c2v[j] - 2.f * acc[j][r];
            float q = 1.f / (1.f + d);
            acc[j][r] = q;
            s += q;
        }
        s += __shfl_xor(s, 1);
        s += __shfl_xor(s, 2);
        s += __shfl_xor(s, 4);
        s += __shfl_xor(s, 8);
        s += __shfl_xor(s, 16);
        if (l31 == 0) rowsum[rr][w] = s;
    }
    __syncthreads();

    // ---- pass 2: normalize + full-line stores ----
#pragma unroll
    for (int r = 0; r < 16; ++r) {
        const int rr = (r & 3) + 8 * (r >> 2) + 4 * hi;
        const float inv = 1.f / (rowsum[rr][0] + rowsum[rr][1] +
                                 rowsum[rr][2] + rowsum[rr][3]);
        float* op = out + (row0 + (size_t)rr) * KC + w * 64 + l31;
#pragma unroll
        for (int j = 0; j < 2; ++j)
            op[j * 32] = acc[j][r] * inv;   // 2 x 128-B full lines / instr
    }
}

extern "C" void kernel_launch(void* const* d_in, const int* in_sizes, int n_in,
                              void* d_out, int out_size, void* d_ws, size_t ws_size,
                              hipStream_t stream) {
    const float* ctx  = (const float*)d_in[0];
    const float* clus = (const float*)d_in[1];
    float* out = (float*)d_out;

    short* wsb = (short*)d_ws;                               // bf16 fragment image
    float* c2  = (float*)((char*)d_ws + CL_SHORTS * 2);      // 256 fp32 norms

    const int nrows = in_sizes[0] / DD;                      // 524288
    const int grid  = nrows / BM;                            // 16384

    hipLaunchKernelGGL(prep_clusters, dim3(KC), dim3(64), 0, stream, clus, wsb, c2);
    hipLaunchKernelGGL(cluster_q_main, dim3(grid), dim3(256), 0, stream,
                       ctx, wsb, c2, out);
}

// Round 6
// 290.943 us; speedup vs baseline: 4.3848x; 1.4537x over previous
//
#include <hip/hip_runtime.h>
#include <hip/hip_bf16.h>

// clusterLayer: q = rownorm( 1 / (1 + ||x||^2 + ||c||^2 - 2 x.cT) )
// N=524288, K=256, D=256. fp32 in/out.
// Kernel 0: clusters fp32 -> bf16 in 32x32x16-MFMA-fragment order
//   (1 KiB per (nj,ks) fragment) + fp32 c2 norms, in d_ws.
// Main (BM=32, 256 thr = 4 waves = 4 col-quarters):
//   - A converted to bf16 ONCE per block into 16-KiB LDS in fragment
//     order [j=k/8][row] (each wave stages its k-quarter; 8 up-front
//     dwordx4 loads/lane -> single HBM latency per block).
//   - K-loop: ds_read_b128 A-frag + 2 global B-frags (L2-hot, 3-slot
//     distance-2 rotation) + 2 MFMA. No per-step conversion.
//   - |x|^2 fp32 partials via LDS; row sums across quarters via LDS.
//   - Full-line stores (verified: WRITE_SIZE == output bytes).

#define DD 256
#define KC 256
#define BM 32
#define CL_SHORTS (KC * DD)            // 65536 shorts = 131072 B

typedef __attribute__((ext_vector_type(4)))  float f32x4;
typedef __attribute__((ext_vector_type(16))) float f32x16;
typedef __attribute__((ext_vector_type(8)))  short bf16x8;
typedef __attribute__((ext_vector_type(4)))  short bf16x4;

__device__ __forceinline__ short f2bf(float f) {
    union { float f; unsigned u; } v; v.f = f;
    unsigned r = (v.u + 0x7fffu + ((v.u >> 16) & 1u)) >> 16;
    return (short)r;
}

__device__ __forceinline__ f32x4 ld4(const float* p) { return *(const f32x4*)p; }

// ---------------- Kernel 0: prep clusters (fragment-order bf16 + norms) ----
__global__ __launch_bounds__(64)
void prep_clusters(const float* __restrict__ clus,
                   short* __restrict__ wsb, float* __restrict__ c2) {
    const int c = blockIdx.x;      // cluster row 0..255
    const int t = threadIdx.x;     // 0..63, 4 floats each
    f32x4 v = *(const f32x4*)(clus + c * DD + t * 4);
    bf16x4 o;
    o[0] = f2bf(v[0]); o[1] = f2bf(v[1]); o[2] = f2bf(v[2]); o[3] = f2bf(v[3]);

    // fragment layout: frag(nj,ks) = 512 contiguous shorts; within it,
    // lane (hi*32+l31) holds clusters[nj*32+l31][ks*16+hi*8 .. +8].
    const int j    = t >> 1;       // 8-elem chunk index within row (k/8)
    const int ks   = j >> 1;
    const int hi   = j & 1;
    const int half = t & 1;        // which 4-elem half of the chunk
    const int nj   = c >> 5;
    const int l31  = c & 31;
    *(bf16x4*)&wsb[(((nj * 16 + ks) * 64 + hi * 32 + l31) << 3) + half * 4] = o;

    float s = v[0]*v[0] + v[1]*v[1] + v[2]*v[2] + v[3]*v[3];
    s += __shfl_xor(s, 1);  s += __shfl_xor(s, 2);  s += __shfl_xor(s, 4);
    s += __shfl_xor(s, 8);  s += __shfl_xor(s, 16); s += __shfl_xor(s, 32);
    if (t == 0) c2[c] = s;
}

// ---------------- Main kernel ----------------
__global__ __launch_bounds__(256, 5)
void cluster_q_main(const float* __restrict__ ctx,
                    const short* __restrict__ wsb,
                    const float* __restrict__ c2g,
                    float* __restrict__ out) {
    __shared__ short Af[32 * 32 * 8];    // 16 KiB: [j=k/8][row][8 shorts]
    __shared__ float x2p4[4][BM];        // per-(wave,row) |x|^2 partials
    __shared__ float rowsum[4][BM];      // per-(quarter,row) q-sums

    const int t    = threadIdx.x;
    const int lane = t & 63;
    const int w    = t >> 6;             // wave = col-quarter 0..3
    const int l31  = lane & 31;
    const int hi   = lane >> 5;
    const size_t row0 = (size_t)blockIdx.x * BM;

    // ---- stage A: wave w converts k-range [w*64, w*64+64) of all 32 rows ----
    {
        const int r    = lane >> 1;      // row 0..31
        const int half = lane & 1;       // 32-float half of the quarter
        const float* src = ctx + (row0 + (size_t)r) * DD + w * 64 + half * 32;
        f32x4 u[8];
#pragma unroll
        for (int i = 0; i < 4; ++i) {    // 8 independent loads, all in flight
            u[2*i]   = ld4(src + i * 8);
            u[2*i+1] = ld4(src + i * 8 + 4);
        }
        float xs = 0.f;
#pragma unroll
        for (int i = 0; i < 4; ++i) {
            f32x4 a0 = u[2*i], a1 = u[2*i+1];
            bf16x8 o;
            o[0] = f2bf(a0[0]); o[1] = f2bf(a0[1]);
            o[2] = f2bf(a0[2]); o[3] = f2bf(a0[3]);
            o[4] = f2bf(a1[0]); o[5] = f2bf(a1[1]);
            o[6] = f2bf(a1[2]); o[7] = f2bf(a1[3]);
            xs += a0[0]*a0[0] + a0[1]*a0[1] + a0[2]*a0[2] + a0[3]*a0[3]
                + a1[0]*a1[0] + a1[1]*a1[1] + a1[2]*a1[2] + a1[3]*a1[3];
            const int j = w * 8 + half * 4 + i;          // k/8 chunk index
            *(bf16x8*)&Af[(j * 32 + r) * 8] = o;
        }
        xs += __shfl_xor(xs, 1);                         // combine halves
        if (half == 0) x2p4[w][r] = xs;
    }

    // B fragment base: global col-tile njg = w*2 + j2, frag (njg*16+ks)*512
    const short* bl = wsb + (size_t)(w * 2 * 16) * 512 + lane * 8;

    __syncthreads();

    // |x|^2 total for row l31 (conflict-free stride-4 reads)
    const float x2l = x2p4[0][l31] + x2p4[1][l31] + x2p4[2][l31] + x2p4[3][l31];

    f32x16 acc[2];
    acc[0] = (f32x16)0.f;
    acc[1] = (f32x16)0.f;

    // B: 3-slot rotation, distance 2
    bf16x8 bs[3][2];
#pragma unroll
    for (int p = 0; p < 2; ++p)
#pragma unroll
        for (int j2 = 0; j2 < 2; ++j2)
            bs[p][j2] = *(const bf16x8*)(bl + (j2 * 16 + p) * 512);

    // A-frag ping-pong from LDS
    bf16x8 afA = *(const bf16x8*)&Af[((0 * 2 + hi) * 32 + l31) * 8];
    bf16x8 afB;

#pragma unroll
    for (int ks = 0; ks < 16; ++ks) {
        const bool even = (ks & 1) == 0;         // compile-time after unroll
        const int cur   = ks % 3;                // compile-time after unroll
        const int nxt   = (ks + 2) % 3;

        // issue B(ks+2) into the free slot
        if (ks < 14) {
#pragma unroll
            for (int j2 = 0; j2 < 2; ++j2)
                bs[nxt][j2] = *(const bf16x8*)(bl + (j2 * 16 + ks + 2) * 512);
        }
        // issue A-frag read for ks+1
        if (ks < 15) {
            bf16x8 v = *(const bf16x8*)&Af[(((ks + 1) * 2 + hi) * 32 + l31) * 8];
            if (even) afB = v; else afA = v;
        }

        const bf16x8 af = even ? afA : afB;
#pragma unroll
        for (int j2 = 0; j2 < 2; ++j2)
            acc[j2] = __builtin_amdgcn_mfma_f32_32x32x16_bf16(
                af, bs[cur][j2], acc[j2], 0, 0, 0);
    }

    float c2v[2];
#pragma unroll
    for (int j2 = 0; j2 < 2; ++j2) c2v[j2] = c2g[w * 64 + j2 * 32 + l31];

    // ---- pass 1: q = 1/(1+d), per-row partial sums -> LDS ----
#pragma unroll
    for (int r = 0; r < 16; ++r) {
        const int rr = (r & 3) + 8 * (r >> 2) + 4 * hi;   // row 0..31
        const float x2r = __shfl(x2l, rr);                // lane rr has row rr
        float s = 0.f;
#pragma unroll
        for (int j2 = 0; j2 < 2; ++j2) {
            float d = x2r + c2v[j2] - 2.f * acc[j2][r];
            float q = 1.f / (1.f + d);
            acc[j2][r] = q;
            s += q;
        }
        s += __shfl_xor(s, 1);
        s += __shfl_xor(s, 2);
        s += __shfl_xor(s, 4);
        s += __shfl_xor(s, 8);
        s += __shfl_xor(s, 16);
        if (l31 == 0) rowsum[w][rr] = s;
    }
    __syncthreads();

    // ---- pass 2: normalize + full-line stores ----
#pragma unroll
    for (int r = 0; r < 16; ++r) {
        const int rr = (r & 3) + 8 * (r >> 2) + 4 * hi;
        const float inv = 1.f / (rowsum[0][rr] + rowsum[1][rr] +
                                 rowsum[2][rr] + rowsum[3][rr]);
        float* op = out + (row0 + (size_t)rr) * KC + w * 64 + l31;
#pragma unroll
        for (int j2 = 0; j2 < 2; ++j2)
            op[j2 * 32] = acc[j2][r] * inv;   // 2 x 128-B full lines / instr
    }
}

extern "C" void kernel_launch(void* const* d_in, const int* in_sizes, int n_in,
                              void* d_out, int out_size, void* d_ws, size_t ws_size,
                              hipStream_t stream) {
    const float* ctx  = (const float*)d_in[0];
    const float* clus = (const float*)d_in[1];
    float* out = (float*)d_out;

    short* wsb = (short*)d_ws;                               // bf16 fragment image
    float* c2  = (float*)((char*)d_ws + CL_SHORTS * 2);      // 256 fp32 norms

    const int nrows = in_sizes[0] / DD;                      // 524288
    const int grid  = nrows / BM;                            // 16384

    hipLaunchKernelGGL(prep_clusters, dim3(KC), dim3(64), 0, stream, clus, wsb, c2);
    hipLaunchKernelGGL(cluster_q_main, dim3(grid), dim3(256), 0, stream,
                       ctx, wsb, c2, out);
}